// Round 5
// baseline (346.851 us; speedup 1.0000x reference)
//
#include <hip/hip_runtime.h>

// LinearSelfAttention: out = rot(q) @ (rot(k)^T @ (w*v)), fp16 MFMA.
// Round 8: 256x256 tile / 8 waves / per-wave 128x64 (acc 8x4) for all
// three GEMMs. R1/R2/R4 showed the 128a-tile 2-barrier structure caps at
// ~490 TF with nothing saturated (MfmaUtil 20, VALU 25, HBM 29): the
// 16-MFMA-per-barrier-pair geometry is the limit. New geometry doubles
// MFMA per barrier (32/wave) and per staged byte (0.375 reads/MFMA,
// m201 ratio). PHASE skeleton + vmcnt ledger are IDENTICAL to the
// verified R7 pipeline (4 loads/tile/wave, vmcnt(4)/(0), pinned
// barriers). LDS 64KB dbuf; qkv epilogue in 2 row-half Ts passes.
//
// ws layout (~133.5 MiB):
//   phi_h  [32768][512] f16   @ 0            (33,554,432 B)  } kvp f16[8] aliases
//   wcat   [1536][512]  f16   @ 33,554,432   ( 1,572,864 B)    phi_h after qkv
//   bcat   [1536]       f32   @ 35,127,296   (     6,144 B)
//   qr     [32768][512] f16   @ 35,133,440   (33,554,432 B)
//   krT    [8][512][4096] f16 @ 68,687,872   (33,554,432 B)
//   vwT    [8][512][4096] f16 @ 102,242,304  (33,554,432 B)
//   kvT    [8][512][512] f16  @ 135,796,736  ( 4,194,304 B)

typedef _Float16 f16x8 __attribute__((ext_vector_type(8)));
typedef _Float16 f16x4 __attribute__((ext_vector_type(4)));
typedef float f32x4 __attribute__((ext_vector_type(4)));

__device__ __forceinline__ void gl_lds16(const void* g, void* l) {
    __builtin_amdgcn_global_load_lds(
        (const __attribute__((address_space(1))) void*)g,
        (__attribute__((address_space(3))) void*)l, 16, 0, 0);
}

// Stage one 256x32 A-tile and 256x32 B-tile (BK=32) into LDS.
// 8 waves x (2 A + 2 B) instructions; each instruction stages 16 rows
// (row = lane>>2, 16B seg = lane&3). 4 vmcnt events per tile per wave --
// SAME ledger as the verified R7 pipeline. sseg carries the inverse XOR
// swizzle (slot ^ (row>>1)&3 within each 64B row) so the linear LDS
// write lands swizzled data.
__device__ __forceinline__ void stage2(const _Float16* gA, size_t sA,
                                       const _Float16* gB, size_t sB,
                                       _Float16* As, _Float16* Bs,
                                       int ca, int srow, int sseg) {
    gl_lds16(&gA[(size_t)(ca * 16 + srow) * sA + sseg], &As[ca * 512]);
    gl_lds16(&gA[(size_t)(ca * 16 + 16 + srow) * sA + sseg], &As[(ca + 1) * 512]);
    gl_lds16(&gB[(size_t)(ca * 16 + srow) * sB + sseg], &Bs[ca * 512]);
    gl_lds16(&gB[(size_t)(ca * 16 + 16 + srow) * sB + sseg], &Bs[(ca + 1) * 512]);
}

// One BK=32 MFMA step (8 waves, 128x64 per wave, 8x4 16x16 frags).
// qs = quad ^ ((l16>>1)&3): swizzled slot, per-thread constant (row bases
// are multiples of 16 so (row>>1)&3 == (l16>>1)&3).
__device__ __forceinline__ void mfma_step(const _Float16* As, const _Float16* Bs,
                                          int wm, int wn, int l16, int qs,
                                          f32x4 acc[8][4]) {
    f16x8 af[8], bf[4];
    #pragma unroll
    for (int mi = 0; mi < 8; mi++)
        af[mi] = *(const f16x8*)&As[(wm + mi * 16 + l16) * 32 + qs * 8];
    #pragma unroll
    for (int ni = 0; ni < 4; ni++)
        bf[ni] = *(const f16x8*)&Bs[(wn + ni * 16 + l16) * 32 + qs * 8];
    #pragma unroll
    for (int mi = 0; mi < 8; mi++)
        #pragma unroll
        for (int ni = 0; ni < 4; ni++)
            acc[mi][ni] = __builtin_amdgcn_mfma_f32_16x16x32_f16(
                af[mi], bf[ni], acc[mi][ni], 0, 0, 0);
}

// One pipeline phase -- byte-identical sync structure to verified R7:
//  - vmcnt(VM) + barrier: consumed tile fully landed for all waves.
//  - lgkmcnt(0) + sched_barrier + barrier: all waves' LDS reads complete
//    before any wave restages the buffer.
#define PHASE(BUFA, BUFB, VM)                                                 \
    asm volatile("s_waitcnt vmcnt(" #VM ")" ::: "memory");                    \
    __builtin_amdgcn_s_barrier();                                             \
    asm volatile("" ::: "memory");                                            \
    __builtin_amdgcn_sched_barrier(0);                                        \
    mfma_step(BUFA, BUFB, wm, wn, l16, qs, acc);                              \
    asm volatile("s_waitcnt lgkmcnt(0)" ::: "memory");                        \
    __builtin_amdgcn_sched_barrier(0);                                        \
    __builtin_amdgcn_s_barrier();                                             \
    asm volatile("" ::: "memory");

// Pipelined K=512 loop: 16 BK=32 tiles, ping-pong As0/As1, depth-2
// prefetch, counted vmcnt (4 = one tile's loads still in flight).
#define PIPE_LOOP(gA, sA, gB, sB)                                             \
    stage2(gA, sA, gB, sB, As0, Bs0, ca, srow, sseg);                         \
    stage2(gA + 32, sA, gB + 32, sB, As1, Bs1, ca, srow, sseg);               \
    _Pragma("unroll")                                                         \
    for (int p = 0; p < 8; p++) {                                             \
        const int t0 = 2 * p;                                                 \
        PHASE(As0, Bs0, 4)                                                    \
        if (t0 + 2 < 16)                                                      \
            stage2(gA + (size_t)(t0 + 2) * 32, sA,                            \
                   gB + (size_t)(t0 + 2) * 32, sB,                            \
                   As0, Bs0, ca, srow, sseg);                                 \
        if (p < 7) { PHASE(As1, Bs1, 4) }                                     \
        else       { PHASE(As1, Bs1, 0) }                                     \
        if (t0 + 3 < 16)                                                      \
            stage2(gA + (size_t)(t0 + 3) * 32, sA,                            \
                   gB + (size_t)(t0 + 3) * 32, sB,                            \
                   As1, Bs1, ca, srow, sseg);                                 \
    }

// ---------------------------------------------------------------- prep ----
__global__ __launch_bounds__(256) void convert_phi(const float* __restrict__ phi,
                                                   _Float16* __restrict__ phi_h) {
    int i = (blockIdx.x * 256 + threadIdx.x) * 4;
    float4 v = *(const float4*)(phi + i);
    f16x4 o = {(_Float16)v.x, (_Float16)v.y, (_Float16)v.z, (_Float16)v.w};
    *(f16x4*)(phi_h + i) = o;
}

__global__ __launch_bounds__(256) void pack_w(
    const float* __restrict__ Wq, const float* __restrict__ Wk,
    const float* __restrict__ Wv, const float* __restrict__ bq,
    const float* __restrict__ bk, const float* __restrict__ bv,
    _Float16* __restrict__ wcat, float* __restrict__ bcat) {
    int j = blockIdx.x;            // 0..1535 output row
    int reg = j >> 9, jr = j & 511;
    const float* W; const float* bias;
    if (reg == 0)      { W = Wq; bias = bq; }
    else if (reg == 1) { W = Wk; bias = bk; }
    else               { W = Wv; bias = bv; }
    int d = (reg < 2) ? ((jr & 1) ? (jr >> 1) + 256 : (jr >> 1)) : jr;
    for (int i = threadIdx.x; i < 512; i += 256)
        wcat[j * 512 + i] = (_Float16)W[d * 512 + i];
    if (threadIdx.x == 0) bcat[j] = bias[d];
}

// ------------------------------------------------------------ QKV GEMM ----
// C[32768][1536] = phi_h @ wcat^T, tile 256x256, pipelined BK=32.
// LDS: 64KB dbuf; epilogue Ts aliases it (q: [128][264], k/v: [256][136]).
__global__ __launch_bounds__(512) void qkv_kernel(
    const _Float16* __restrict__ phi_h, const _Float16* __restrict__ wcat,
    const float* __restrict__ bcat, const float* __restrict__ coords,
    const float* __restrict__ weights, const float* __restrict__ Wrot,
    _Float16* __restrict__ qr, _Float16* __restrict__ krT,
    _Float16* __restrict__ vwT) {
    __shared__ __align__(16) char smem[69632];
    _Float16* As0 = (_Float16*)smem;
    _Float16* Bs0 = (_Float16*)(smem + 16384);
    _Float16* As1 = (_Float16*)(smem + 32768);
    _Float16* Bs1 = (_Float16*)(smem + 49152);
    _Float16* Ts  = (_Float16*)smem;

    const int tid = threadIdx.x;
    const int lane = tid & 63, wave = tid >> 6;
    const int quad = lane >> 4, l16 = lane & 15;
    const int qs = quad ^ ((l16 >> 1) & 3);           // swizzled read slot
    const int wr = wave >> 2, wc = wave & 3;
    const int wm = wr * 128, wn = wc * 64;
    const int m0 = blockIdx.y * 256;      // row tile (over B*N)
    const int c0 = blockIdx.x * 256;      // col tile (over 1536)
    const int ca = wave * 2;
    const int srow = lane >> 2;
    const int sseg = (((lane & 3) ^ ((lane >> 3) & 3)) * 8);  // inv-swizzled src

    const _Float16* gA = phi_h + (size_t)m0 * 512;
    const _Float16* gB = wcat + (size_t)c0 * 512;

    f32x4 acc[8][4] = {};

    PIPE_LOOP(gA, 512, gB, 512)

    const int region = c0 >> 9;   // 0=q, 1=k, 2=v (256 | 512: never straddles)
    const float qscale = 0.04419417382415922f;  // 1/sqrt(512)

    float bias[4], w0[4], w1[4], w2[4];
    #pragma unroll
    for (int ni = 0; ni < 4; ni++) {
        int gc = c0 + wn + ni * 16 + l16;
        bias[ni] = bcat[gc];
        if (region < 2) {
            int jp = (gc & 511) >> 1;
            w0[ni] = Wrot[jp * 3];
            w1[ni] = Wrot[jp * 3 + 1];
            w2[ni] = Wrot[jp * 3 + 2];
        }
    }

    // Two row-half passes: waves with wr==rh write their 128x64 into Ts,
    // then all 512 threads copy out 128x256 coalesced.
    const int b = m0 >> 12, n0 = m0 & 4095, cb = c0 & 511;
    _Float16* dstT = (region == 1) ? krT : vwT;
    for (int rh = 0; rh < 2; rh++) {
        if (rh) __syncthreads();              // prev copy done before overwrite
        if (wr == rh) {
            #pragma unroll
            for (int mi = 0; mi < 8; mi++)
                #pragma unroll
                for (int r = 0; r < 4; r++) {
                    int row = mi * 16 + quad * 4 + r;        // local 0..127
                    int gm = m0 + rh * 128 + row;
                    if (region == 0) {
                        float x = coords[gm * 3], y = coords[gm * 3 + 1],
                              z = coords[gm * 3 + 2];
                        #pragma unroll
                        for (int ni = 0; ni < 4; ni++) {
                            float val = (acc[mi][ni][r] + bias[ni]) * qscale;
                            float part = __shfl_xor(val, 1);
                            float ph = x * w0[ni] + y * w1[ni] + z * w2[ni];
                            float sv, cv; __sincosf(ph, &sv, &cv);
                            float res = (l16 & 1) ? (part * sv + val * cv)
                                                  : (val * cv - part * sv);
                            Ts[row * 264 + wn + ni * 16 + l16] = (_Float16)res;
                        }
                    } else if (region == 1) {
                        float x = coords[gm * 3], y = coords[gm * 3 + 1],
                              z = coords[gm * 3 + 2];
                        #pragma unroll
                        for (int ni = 0; ni < 4; ni++) {
                            float val = acc[mi][ni][r] + bias[ni];
                            float part = __shfl_xor(val, 1);
                            float ph = x * w0[ni] + y * w1[ni] + z * w2[ni];
                            float sv, cv; __sincosf(ph, &sv, &cv);
                            float res = (l16 & 1) ? (part * sv + val * cv)
                                                  : (val * cv - part * sv);
                            Ts[(wn + ni * 16 + l16) * 136 + row] = (_Float16)res;
                        }
                    } else {
                        float wgt = weights[gm];
                        #pragma unroll
                        for (int ni = 0; ni < 4; ni++) {
                            float val = (acc[mi][ni][r] + bias[ni]) * wgt;
                            Ts[(wn + ni * 16 + l16) * 136 + row] = (_Float16)val;
                        }
                    }
                }
        }
        __syncthreads();
        if (region == 0) {
            for (int i = tid; i < 4096; i += 512) {
                int row = i >> 5, cv = (i & 31) * 8;
                *(f16x8*)&qr[(size_t)(m0 + rh * 128 + row) * 512 + c0 + cv] =
                    *(f16x8*)&Ts[row * 264 + cv];
            }
        } else {
            for (int i = tid; i < 4096; i += 512) {
                int col = i >> 4, rv = (i & 15) * 8;
                *(f16x8*)&dstT[((size_t)b * 512 + cb + col) * 4096 +
                               n0 + rh * 128 + rv] = *(f16x8*)&Ts[col * 136 + rv];
            }
        }
    }
}

// ------------------------------------------------------------- kv GEMM ----
// kvp[s][b][e][d] (f16) = sum_{n in split s} vwT[b][e][n]*krT[b][d][n];
// tile 256x256, split-K x8 (K=512 each), pipelined BK=32.
__global__ __launch_bounds__(512) void kv_kernel(
    const _Float16* __restrict__ vwT, const _Float16* __restrict__ krT,
    _Float16* __restrict__ kvp) {
    __shared__ __align__(16) char smem[65536];
    _Float16* As0 = (_Float16*)smem;
    _Float16* Bs0 = (_Float16*)(smem + 16384);
    _Float16* As1 = (_Float16*)(smem + 32768);
    _Float16* Bs1 = (_Float16*)(smem + 49152);
    const int tid = threadIdx.x, lane = tid & 63, wave = tid >> 6;
    const int quad = lane >> 4, l16 = lane & 15;
    const int qs = quad ^ ((l16 >> 1) & 3);
    const int wm = (wave >> 2) * 128, wn = (wave & 3) * 64;
    const int d0 = blockIdx.x * 256, e0 = blockIdx.y * 256;
    const int b = blockIdx.z >> 3, split = blockIdx.z & 7;
    const int ca = wave * 2;
    const int srow = lane >> 2;
    const int sseg = (((lane & 3) ^ ((lane >> 3) & 3)) * 8);
    const size_t base = (size_t)b * 512 * 4096;
    const int kbeg = split * 512;
    const _Float16* gA = vwT + base + (size_t)e0 * 4096 + kbeg;
    const _Float16* gB = krT + base + (size_t)d0 * 4096 + kbeg;
    f32x4 acc[8][4] = {};

    PIPE_LOOP(gA, 4096, gB, 4096)

    _Float16* dst = kvp + ((size_t)split * 8 + b) * 262144;
    #pragma unroll
    for (int mi = 0; mi < 8; mi++)
        #pragma unroll
        for (int ni = 0; ni < 4; ni++)
            #pragma unroll
            for (int r = 0; r < 4; r++) {
                int e = e0 + wm + mi * 16 + quad * 4 + r;
                int d = d0 + wn + ni * 16 + l16;
                dst[e * 512 + d] = (_Float16)acc[mi][ni][r];
            }
}

// kvT[b][e][d] f16 = sum_s kvp[s][b][e][d]
__global__ __launch_bounds__(256) void reduce_kv(const _Float16* __restrict__ kvp,
                                                 _Float16* __restrict__ kvT) {
    int i = (blockIdx.x * 256 + threadIdx.x) * 8;
    float s[8] = {};
    #pragma unroll
    for (int sp = 0; sp < 8; sp++) {
        f16x8 v = *(const f16x8*)(kvp + (size_t)sp * 2097152 + i);
        #pragma unroll
        for (int j = 0; j < 8; j++) s[j] += (float)v[j];
    }
    f16x8 o;
    #pragma unroll
    for (int j = 0; j < 8; j++) o[j] = (_Float16)s[j];
    *(f16x8*)(kvT + i) = o;
}

// ------------------------------------------------------------ out GEMM ----
// out[gm][e] = sum_d qr[gm][d] * kvT[b][e][d]; tile 256x256, pipelined BK=32.
__global__ __launch_bounds__(512) void out_kernel(
    const _Float16* __restrict__ qr, const _Float16* __restrict__ kvT,
    float* __restrict__ out) {
    __shared__ __align__(16) char smem[65536];
    _Float16* As0 = (_Float16*)smem;
    _Float16* Bs0 = (_Float16*)(smem + 16384);
    _Float16* As1 = (_Float16*)(smem + 32768);
    _Float16* Bs1 = (_Float16*)(smem + 49152);
    const int tid = threadIdx.x, lane = tid & 63, wave = tid >> 6;
    const int quad = lane >> 4, l16 = lane & 15;
    const int qs = quad ^ ((l16 >> 1) & 3);
    const int wm = (wave >> 2) * 128, wn = (wave & 3) * 64;
    const int m0 = blockIdx.y * 256, e0 = blockIdx.x * 256;
    const int b = m0 >> 12;
    const int ca = wave * 2;
    const int srow = lane >> 2;
    const int sseg = (((lane & 3) ^ ((lane >> 3) & 3)) * 8);
    const _Float16* gA = qr + (size_t)m0 * 512;
    const _Float16* gB = kvT + (size_t)b * 262144 + (size_t)e0 * 512;
    f32x4 acc[8][4] = {};

    PIPE_LOOP(gA, 512, gB, 512)

    #pragma unroll
    for (int mi = 0; mi < 8; mi++)
        #pragma unroll
        for (int ni = 0; ni < 4; ni++)
            #pragma unroll
            for (int r = 0; r < 4; r++) {
                int gm = m0 + wm + mi * 16 + quad * 4 + r;
                int e = e0 + wn + ni * 16 + l16;
                out[(size_t)gm * 512 + e] = acc[mi][ni][r];
            }
}

// -------------------------------------------------------------- launch ----
extern "C" void kernel_launch(void* const* d_in, const int* in_sizes, int n_in,
                              void* d_out, int out_size, void* d_ws, size_t ws_size,
                              hipStream_t stream) {
    const float* phi     = (const float*)d_in[0];
    const float* coords  = (const float*)d_in[1];
    const float* weights = (const float*)d_in[2];
    const float* Wq      = (const float*)d_in[3];
    const float* bq      = (const float*)d_in[4];
    const float* Wk      = (const float*)d_in[5];
    const float* bk      = (const float*)d_in[6];
    const float* Wv      = (const float*)d_in[7];
    const float* bv      = (const float*)d_in[8];
    const float* Wrot    = (const float*)d_in[9];
    float* out = (float*)d_out;

    char* ws = (char*)d_ws;
    _Float16* phi_h = (_Float16*)(ws);
    _Float16* kvp   = (_Float16*)(ws);            // aliases phi_h (dead by then)
    _Float16* wcat  = (_Float16*)(ws + 33554432);
    float*    bcat  = (float*)   (ws + 35127296);
    _Float16* qr    = (_Float16*)(ws + 35133440);
    _Float16* krT   = (_Float16*)(ws + 68687872);
    _Float16* vwT   = (_Float16*)(ws + 102242304);
    _Float16* kvT   = (_Float16*)(ws + 135796736);  // end: 139,991,040 B

    convert_phi<<<16384, 256, 0, stream>>>(phi, phi_h);
    pack_w<<<1536, 256, 0, stream>>>(Wq, Wk, Wv, bq, bk, bv, wcat, bcat);
    qkv_kernel<<<dim3(6, 128), 512, 0, stream>>>(phi_h, wcat, bcat, coords,
                                                 weights, Wrot, qr, krT, vwT);
    kv_kernel<<<dim3(2, 2, 64), 512, 0, stream>>>(vwT, krT, kvp);
    reduce_kv<<<1024, 256, 0, stream>>>(kvp, kvT);
    out_kernel<<<dim3(2, 128), 512, 0, stream>>>(qr, kvT, out);
}

// Round 6
// 271.756 us; speedup vs baseline: 1.2763x; 1.2763x over previous
//
#include <hip/hip_runtime.h>

// LinearSelfAttention: out = rot(q) @ (rot(k)^T @ (w*v)), fp16 MFMA.
// Round 9: geometry reverted to the verified R7/128^2 pipeline (R8's
// 256^2-at-2-barrier regressed 105->166 us, confirming the guide's
// tile/structure rule). Added on top of the byte-identical R7 template:
//  (1) bijective XCD swizzle (T1) in all three GEMMs -- groups the 12
//      column-tiles sharing a phi slab (qkv), each (b,split) panel pair
//      (kv), and each kvT[b] (out) onto ONE XCD's L2. qkv FETCH_SIZE was
//      136 MB vs 35 MB ideal (slab re-fetched by ~4 XCDs).
//  (2) s_setprio(1) around the MFMA cluster (T5) -- 4 independent
//      blocks/CU give the inter-wave role diversity where setprio pays.
//
// ws layout (~133.5 MiB):
//   phi_h  [32768][512] f16   @ 0            (33,554,432 B)  } kvp f16[8] aliases
//   wcat   [1536][512]  f16   @ 33,554,432   ( 1,572,864 B)    phi_h after qkv
//   bcat   [1536]       f32   @ 35,127,296   (     6,144 B)
//   qr     [32768][512] f16   @ 35,133,440   (33,554,432 B)
//   krT    [8][512][4096] f16 @ 68,687,872   (33,554,432 B)
//   vwT    [8][512][4096] f16 @ 102,242,304  (33,554,432 B)
//   kvT    [8][512][512] f16  @ 135,796,736  ( 4,194,304 B)

typedef _Float16 f16x8 __attribute__((ext_vector_type(8)));
typedef _Float16 f16x4 __attribute__((ext_vector_type(4)));
typedef float f32x4 __attribute__((ext_vector_type(4)));

__device__ __forceinline__ void gl_lds16(const void* g, void* l) {
    __builtin_amdgcn_global_load_lds(
        (const __attribute__((address_space(1))) void*)g,
        (__attribute__((address_space(3))) void*)l, 16, 0, 0);
}

// Stage one 128x32 A-tile and B-tile (BK=32) into LDS (4 global_load_lds
// per wave = 4 vmcnt events). sseg carries the inverse XOR swizzle
// (slot ^ (row>>1)&3 within each 64B row) so the linear LDS write lands
// swizzled data.
__device__ __forceinline__ void stage2(const _Float16* gA, size_t sA,
                                       const _Float16* gB, size_t sB,
                                       _Float16* As, _Float16* Bs,
                                       int ca, int srow, int sseg) {
    gl_lds16(&gA[(size_t)(ca * 16 + srow) * sA + sseg], &As[ca * 512]);
    gl_lds16(&gA[(size_t)(ca * 16 + 16 + srow) * sA + sseg], &As[(ca + 1) * 512]);
    gl_lds16(&gB[(size_t)(ca * 16 + srow) * sB + sseg], &Bs[ca * 512]);
    gl_lds16(&gB[(size_t)(ca * 16 + 16 + srow) * sB + sseg], &Bs[(ca + 1) * 512]);
}

// One BK=32 MFMA step from LDS tiles (4 waves, 64x64 per wave, 4x4 16x16).
// qs = quad ^ ((l16>>1)&3): swizzled slot, per-thread constant.
__device__ __forceinline__ void mfma_step(const _Float16* As, const _Float16* Bs,
                                          int wm, int wn, int l16, int qs,
                                          f32x4 acc[4][4]) {
    f16x8 af[4], bf[4];
    #pragma unroll
    for (int mi = 0; mi < 4; mi++)
        af[mi] = *(const f16x8*)&As[(wm + mi * 16 + l16) * 32 + qs * 8];
    #pragma unroll
    for (int ni = 0; ni < 4; ni++)
        bf[ni] = *(const f16x8*)&Bs[(wn + ni * 16 + l16) * 32 + qs * 8];
    #pragma unroll
    for (int mi = 0; mi < 4; mi++)
        #pragma unroll
        for (int ni = 0; ni < 4; ni++)
            acc[mi][ni] = __builtin_amdgcn_mfma_f32_16x16x32_f16(
                af[mi], bf[ni], acc[mi][ni], 0, 0, 0);
}

// One pipeline phase -- sync structure identical to the verified R7:
//  - vmcnt(VM) + barrier: consumed tile fully landed for all waves.
//  - lgkmcnt(0) + sched_barrier + barrier: all waves' LDS reads complete
//    before any wave restages the buffer.
// setprio(1) brackets the MFMA cluster (T5; safe, no reordering effect).
#define PHASE(BUFA, BUFB, VM)                                                 \
    asm volatile("s_waitcnt vmcnt(" #VM ")" ::: "memory");                    \
    __builtin_amdgcn_s_barrier();                                             \
    asm volatile("" ::: "memory");                                            \
    __builtin_amdgcn_sched_barrier(0);                                        \
    __builtin_amdgcn_s_setprio(1);                                            \
    mfma_step(BUFA, BUFB, wm, wn, l16, qs, acc);                              \
    __builtin_amdgcn_s_setprio(0);                                            \
    asm volatile("s_waitcnt lgkmcnt(0)" ::: "memory");                        \
    __builtin_amdgcn_sched_barrier(0);                                        \
    __builtin_amdgcn_s_barrier();                                             \
    asm volatile("" ::: "memory");

// Pipelined K=512 loop: 16 BK=32 tiles, ping-pong As0/As1, depth-2
// prefetch, counted vmcnt (4 = one tile's loads still in flight).
#define PIPE_LOOP(gA, sA, gB, sB)                                             \
    stage2(gA, sA, gB, sB, As0, Bs0, ca, srow, sseg);                         \
    stage2(gA + 32, sA, gB + 32, sB, As1, Bs1, ca, srow, sseg);               \
    _Pragma("unroll")                                                         \
    for (int p = 0; p < 8; p++) {                                             \
        const int t0 = 2 * p;                                                 \
        PHASE(As0, Bs0, 4)                                                    \
        if (t0 + 2 < 16)                                                      \
            stage2(gA + (size_t)(t0 + 2) * 32, sA,                            \
                   gB + (size_t)(t0 + 2) * 32, sB,                            \
                   As0, Bs0, ca, srow, sseg);                                 \
        if (p < 7) { PHASE(As1, Bs1, 4) }                                     \
        else       { PHASE(As1, Bs1, 0) }                                     \
        if (t0 + 3 < 16)                                                      \
            stage2(gA + (size_t)(t0 + 3) * 32, sA,                            \
                   gB + (size_t)(t0 + 3) * 32, sB,                            \
                   As1, Bs1, ca, srow, sseg);                                 \
    }

// ---------------------------------------------------------------- prep ----
__global__ __launch_bounds__(256) void convert_phi(const float* __restrict__ phi,
                                                   _Float16* __restrict__ phi_h) {
    int i = (blockIdx.x * 256 + threadIdx.x) * 4;
    float4 v = *(const float4*)(phi + i);
    f16x4 o = {(_Float16)v.x, (_Float16)v.y, (_Float16)v.z, (_Float16)v.w};
    *(f16x4*)(phi_h + i) = o;
}

__global__ __launch_bounds__(256) void pack_w(
    const float* __restrict__ Wq, const float* __restrict__ Wk,
    const float* __restrict__ Wv, const float* __restrict__ bq,
    const float* __restrict__ bk, const float* __restrict__ bv,
    _Float16* __restrict__ wcat, float* __restrict__ bcat) {
    int j = blockIdx.x;            // 0..1535 output row
    int reg = j >> 9, jr = j & 511;
    const float* W; const float* bias;
    if (reg == 0)      { W = Wq; bias = bq; }
    else if (reg == 1) { W = Wk; bias = bk; }
    else               { W = Wv; bias = bv; }
    int d = (reg < 2) ? ((jr & 1) ? (jr >> 1) + 256 : (jr >> 1)) : jr;
    for (int i = threadIdx.x; i < 512; i += 256)
        wcat[j * 512 + i] = (_Float16)W[d * 512 + i];
    if (threadIdx.x == 0) bcat[j] = bias[d];
}

// ------------------------------------------------------------ QKV GEMM ----
// C[32768][1536] = phi_h @ wcat^T, tile 128x128, pipelined BK=32.
// XCD swizzle: nwg=3072, XCD c owns swz in [384c,384c+384) = 32 full row
// slabs (12 col-tiles each) -> each phi slab fetched by ONE L2.
__global__ __launch_bounds__(256) void qkv_kernel(
    const _Float16* __restrict__ phi_h, const _Float16* __restrict__ wcat,
    const float* __restrict__ bcat, const float* __restrict__ coords,
    const float* __restrict__ weights, const float* __restrict__ Wrot,
    _Float16* __restrict__ qr, _Float16* __restrict__ krT,
    _Float16* __restrict__ vwT) {
    __shared__ __align__(16) char smem[34816];          // Ts 128x136 f16 alias
    _Float16* As0 = (_Float16*)smem;
    _Float16* Bs0 = (_Float16*)(smem + 8192);
    _Float16* As1 = (_Float16*)(smem + 16384);
    _Float16* Bs1 = (_Float16*)(smem + 24576);
    _Float16* Ts  = (_Float16*)smem;

    const int tid = threadIdx.x;
    const int lane = tid & 63, wave = tid >> 6;
    const int quad = lane >> 4, l16 = lane & 15;
    const int qs = quad ^ ((l16 >> 1) & 3);           // swizzled read slot
    const int wm = (wave >> 1) * 64, wn = (wave & 1) * 64;
    const int flat = blockIdx.x + blockIdx.y * 12;
    const int swz = (flat & 7) * 384 + (flat >> 3);   // bijective (3072%8==0)
    const int c0 = (swz % 12) * 128;      // col tile (over 1536)
    const int m0 = (swz / 12) * 128;      // row tile (over B*N)
    const int ca = wave * 2;
    const int srow = lane >> 2;
    const int sseg = (((lane & 3) ^ ((lane >> 3) & 3)) * 8);  // inv-swizzled src

    const _Float16* gA = phi_h + (size_t)m0 * 512;
    const _Float16* gB = wcat + (size_t)c0 * 512;

    f32x4 acc[4][4] = {};

    PIPE_LOOP(gA, 512, gB, 512)

    const int region = c0 >> 9;   // 0=q, 1=k, 2=v (128 | 512: never straddles)
    const float qscale = 0.04419417382415922f;  // 1/sqrt(512)

    float bias[4], w0[4], w1[4], w2[4];
    #pragma unroll
    for (int ni = 0; ni < 4; ni++) {
        int gc = c0 + wn + ni * 16 + l16;
        bias[ni] = bcat[gc];
        if (region < 2) {
            int jp = (gc & 511) >> 1;
            w0[ni] = Wrot[jp * 3];
            w1[ni] = Wrot[jp * 3 + 1];
            w2[ni] = Wrot[jp * 3 + 2];
        }
    }

    if (region == 0) {
        // q: rotary + scale -> Ts[row][col] -> coalesced qr store
        #pragma unroll
        for (int mi = 0; mi < 4; mi++)
            #pragma unroll
            for (int r = 0; r < 4; r++) {
                int row = wm + mi * 16 + quad * 4 + r;
                int gm = m0 + row;
                float x = coords[gm * 3], y = coords[gm * 3 + 1], z = coords[gm * 3 + 2];
                #pragma unroll
                for (int ni = 0; ni < 4; ni++) {
                    float val = (acc[mi][ni][r] + bias[ni]) * qscale;
                    float part = __shfl_xor(val, 1);
                    float ph = x * w0[ni] + y * w1[ni] + z * w2[ni];
                    float sv, cv; __sincosf(ph, &sv, &cv);
                    float res = (l16 & 1) ? (part * sv + val * cv)
                                          : (val * cv - part * sv);
                    Ts[row * 136 + wn + ni * 16 + l16] = (_Float16)res;
                }
            }
        __syncthreads();
        for (int i = tid; i < 2048; i += 256) {
            int row = i >> 4, cv = (i & 15) * 8;
            *(f16x8*)&qr[(m0 + row) * 512 + c0 + cv] = *(f16x8*)&Ts[row * 136 + cv];
        }
    } else {
        // k: rotary; v: *weights. -> Ts[col][row] -> coalesced [b][col][n]
        #pragma unroll
        for (int mi = 0; mi < 4; mi++)
            #pragma unroll
            for (int r = 0; r < 4; r++) {
                int row = wm + mi * 16 + quad * 4 + r;
                int gm = m0 + row;
                if (region == 1) {
                    float x = coords[gm * 3], y = coords[gm * 3 + 1], z = coords[gm * 3 + 2];
                    #pragma unroll
                    for (int ni = 0; ni < 4; ni++) {
                        float val = acc[mi][ni][r] + bias[ni];
                        float part = __shfl_xor(val, 1);
                        float ph = x * w0[ni] + y * w1[ni] + z * w2[ni];
                        float sv, cv; __sincosf(ph, &sv, &cv);
                        float res = (l16 & 1) ? (part * sv + val * cv)
                                              : (val * cv - part * sv);
                        Ts[(wn + ni * 16 + l16) * 136 + row] = (_Float16)res;
                    }
                } else {
                    float wgt = weights[gm];
                    #pragma unroll
                    for (int ni = 0; ni < 4; ni++) {
                        float val = (acc[mi][ni][r] + bias[ni]) * wgt;
                        Ts[(wn + ni * 16 + l16) * 136 + row] = (_Float16)val;
                    }
                }
            }
        __syncthreads();
        _Float16* dst = (region == 1) ? krT : vwT;
        const int b = m0 >> 12, n0 = m0 & 4095, cb = c0 & 511;
        for (int i = tid; i < 2048; i += 256) {
            int col = i >> 4, rv = (i & 15) * 8;
            *(f16x8*)&dst[((size_t)b * 512 + cb + col) * 4096 + n0 + rv] =
                *(f16x8*)&Ts[col * 136 + rv];
        }
    }
}

// ------------------------------------------------------------- kv GEMM ----
// kvp[s][b][e][d] (f16) = sum_{n in split s} vwT[b][e][n]*krT[b][d][n];
// tile 128x128, split-K x8 (K=512 each), pipelined BK=32.
// XCD swizzle: nwg=1024, XCD c owns 8 full (b,split) groups -> each
// 1 MB krT/vwT panel pair read by ONE L2.
__global__ __launch_bounds__(256) void kv_kernel(
    const _Float16* __restrict__ vwT, const _Float16* __restrict__ krT,
    _Float16* __restrict__ kvp) {
    __shared__ __align__(16) char smem[32768];
    _Float16* As0 = (_Float16*)smem;
    _Float16* Bs0 = (_Float16*)(smem + 8192);
    _Float16* As1 = (_Float16*)(smem + 16384);
    _Float16* Bs1 = (_Float16*)(smem + 24576);
    const int tid = threadIdx.x, lane = tid & 63, wave = tid >> 6;
    const int quad = lane >> 4, l16 = lane & 15;
    const int qs = quad ^ ((l16 >> 1) & 3);
    const int wm = (wave >> 1) * 64, wn = (wave & 1) * 64;
    const int flat = blockIdx.x + blockIdx.y * 4 + blockIdx.z * 16;
    const int swz = (flat & 7) * 128 + (flat >> 3);   // bijective (1024%8==0)
    const int d0 = (swz & 3) * 128, e0 = ((swz >> 2) & 3) * 128;
    const int zz = swz >> 4;
    const int b = zz >> 3, split = zz & 7;
    const int ca = wave * 2;
    const int srow = lane >> 2;
    const int sseg = (((lane & 3) ^ ((lane >> 3) & 3)) * 8);
    const size_t base = (size_t)b * 512 * 4096;
    const int kbeg = split * 512;
    const _Float16* gA = vwT + base + (size_t)e0 * 4096 + kbeg;
    const _Float16* gB = krT + base + (size_t)d0 * 4096 + kbeg;
    f32x4 acc[4][4] = {};

    PIPE_LOOP(gA, 4096, gB, 4096)

    _Float16* dst = kvp + ((size_t)split * 8 + b) * 262144;
    #pragma unroll
    for (int mi = 0; mi < 4; mi++)
        #pragma unroll
        for (int ni = 0; ni < 4; ni++)
            #pragma unroll
            for (int r = 0; r < 4; r++) {
                int e = e0 + wm + mi * 16 + quad * 4 + r;
                int d = d0 + wn + ni * 16 + l16;
                dst[e * 512 + d] = (_Float16)acc[mi][ni][r];
            }
}

// kvT[b][e][d] f16 = sum_s kvp[s][b][e][d]
__global__ __launch_bounds__(256) void reduce_kv(const _Float16* __restrict__ kvp,
                                                 _Float16* __restrict__ kvT) {
    int i = (blockIdx.x * 256 + threadIdx.x) * 8;
    float s[8] = {};
    #pragma unroll
    for (int sp = 0; sp < 8; sp++) {
        f16x8 v = *(const f16x8*)(kvp + (size_t)sp * 2097152 + i);
        #pragma unroll
        for (int j = 0; j < 8; j++) s[j] += (float)v[j];
    }
    f16x8 o;
    #pragma unroll
    for (int j = 0; j < 8; j++) o[j] = (_Float16)s[j];
    *(f16x8*)(kvT + i) = o;
}

// ------------------------------------------------------------ out GEMM ----
// out[gm][e] = sum_d qr[gm][d] * kvT[b][e][d]; tile 128x128, pipelined BK=32.
// XCD swizzle: nwg=1024, XCD c owns 32 consecutive row slabs = exactly
// one batch b -> kvT[b] (524 KB) resident in ONE L2.
__global__ __launch_bounds__(256) void out_kernel(
    const _Float16* __restrict__ qr, const _Float16* __restrict__ kvT,
    float* __restrict__ out) {
    __shared__ __align__(16) char smem[32768];
    _Float16* As0 = (_Float16*)smem;
    _Float16* Bs0 = (_Float16*)(smem + 8192);
    _Float16* As1 = (_Float16*)(smem + 16384);
    _Float16* Bs1 = (_Float16*)(smem + 24576);
    const int tid = threadIdx.x, lane = tid & 63, wave = tid >> 6;
    const int quad = lane >> 4, l16 = lane & 15;
    const int qs = quad ^ ((l16 >> 1) & 3);
    const int wm = (wave >> 1) * 64, wn = (wave & 1) * 64;
    const int flat = blockIdx.x + blockIdx.y * 4;
    const int swz = (flat & 7) * 128 + (flat >> 3);   // bijective (1024%8==0)
    const int e0 = (swz & 3) * 128, m0 = (swz >> 2) * 128;
    const int b = m0 >> 12;
    const int ca = wave * 2;
    const int srow = lane >> 2;
    const int sseg = (((lane & 3) ^ ((lane >> 3) & 3)) * 8);
    const _Float16* gA = qr + (size_t)m0 * 512;
    const _Float16* gB = kvT + (size_t)b * 262144 + (size_t)e0 * 512;
    f32x4 acc[4][4] = {};

    PIPE_LOOP(gA, 512, gB, 512)

    #pragma unroll
    for (int mi = 0; mi < 4; mi++)
        #pragma unroll
        for (int ni = 0; ni < 4; ni++)
            #pragma unroll
            for (int r = 0; r < 4; r++) {
                int gm = m0 + wm + mi * 16 + quad * 4 + r;
                int e = e0 + wn + ni * 16 + l16;
                out[(size_t)gm * 512 + e] = acc[mi][ni][r];
            }
}

// -------------------------------------------------------------- launch ----
extern "C" void kernel_launch(void* const* d_in, const int* in_sizes, int n_in,
                              void* d_out, int out_size, void* d_ws, size_t ws_size,
                              hipStream_t stream) {
    const float* phi     = (const float*)d_in[0];
    const float* coords  = (const float*)d_in[1];
    const float* weights = (const float*)d_in[2];
    const float* Wq      = (const float*)d_in[3];
    const float* bq      = (const float*)d_in[4];
    const float* Wk      = (const float*)d_in[5];
    const float* bk      = (const float*)d_in[6];
    const float* Wv      = (const float*)d_in[7];
    const float* bv      = (const float*)d_in[8];
    const float* Wrot    = (const float*)d_in[9];
    float* out = (float*)d_out;

    char* ws = (char*)d_ws;
    _Float16* phi_h = (_Float16*)(ws);
    _Float16* kvp   = (_Float16*)(ws);            // aliases phi_h (dead by then)
    _Float16* wcat  = (_Float16*)(ws + 33554432);
    float*    bcat  = (float*)   (ws + 35127296);
    _Float16* qr    = (_Float16*)(ws + 35133440);
    _Float16* krT   = (_Float16*)(ws + 68687872);
    _Float16* vwT   = (_Float16*)(ws + 102242304);
    _Float16* kvT   = (_Float16*)(ws + 135796736);  // end: 139,991,040 B

    convert_phi<<<16384, 256, 0, stream>>>(phi, phi_h);
    pack_w<<<1536, 256, 0, stream>>>(Wq, Wk, Wv, bq, bk, bv, wcat, bcat);
    qkv_kernel<<<dim3(12, 256), 256, 0, stream>>>(phi_h, wcat, bcat, coords,
                                                  weights, Wrot, qr, krT, vwT);
    kv_kernel<<<dim3(4, 4, 64), 256, 0, stream>>>(vwT, krT, kvp);
    reduce_kv<<<1024, 256, 0, stream>>>(kvp, kvT);
    out_kernel<<<dim3(4, 256), 256, 0, stream>>>(qr, kvT, out);
}